// Round 6
// baseline (529.375 us; speedup 1.0000x reference)
//
#include <hip/hip_runtime.h>
#include <cfloat>

#define N_Q     65536
#define D_DIM   256
#define K_CODES 1024
#define DELTA   0.004f
#define SW_CAP  1536

// output float offsets (tuple concatenated flat, all as float32)
#define OUT_QST   0
#define OUT_LOSS  16777216
#define OUT_IDX   16777217
#define OUT_EMBED 16842753
#define OUT_COUNT 17104897
#define OUT_EMAW  17105921

// workspace byte offsets
#define WS_IDX    0u         // 65536*4 int argmin
#define WS_ZZ     262144u    // 65536*4 float ||z||^2
#define WS_PERM   524288u    // 65536*4 int CSR permutation
#define WS_PACK   786432u    // 65536*8 uint64 packed (dist,idx), memset 0xFF
#define WS_EN     1310720u   // 1024*4 float ||e||^2
#define WS_ICNT   1314816u   // 1024*4 int counts, zeroed
#define WS_OFFS   1318912u   // 1024*4 int CSR offsets
#define WS_OFFW   1323008u   // 1024*4 int CSR fill cursor
#define WS_CNTF   1327104u   // 1024*4 float counts
#define WS_CS     1331200u   // 1024*4 float laplace-smoothed counts
#define WS_LOSSB  1335296u   // 1024*8 double loss buckets, zeroed
#define WS_EBF    1343488u   // 1024*256*2 bf16 codebook

typedef short          bf16x8 __attribute__((ext_vector_type(8)));
typedef unsigned short u16x8  __attribute__((ext_vector_type(8)));
typedef unsigned short u16x4  __attribute__((ext_vector_type(4)));
typedef float          f32x4  __attribute__((ext_vector_type(4)));

__device__ inline unsigned short f2bf(float x) {   // RNE fp32 -> bf16
    unsigned u = __float_as_uint(x);
    u += 0x7FFFu + ((u >> 16) & 1u);
    return (unsigned short)(u >> 16);
}
__device__ inline bf16x8 pack8(float4 a, float4 b) {
    u16x8 p;
    p[0]=f2bf(a.x); p[1]=f2bf(a.y); p[2]=f2bf(a.z); p[3]=f2bf(a.w);
    p[4]=f2bf(b.x); p[5]=f2bf(b.y); p[6]=f2bf(b.z); p[7]=f2bf(b.w);
    return *(bf16x8*)&p;
}

// ---------------------------------------------------------------------------
// row-wise sum of squares for a [rows, 256] fp32 matrix; one wave per row.
// Optionally also writes the bf16 (RNE) copy of the row.
__global__ void rownorm2_kernel(const float* __restrict__ x, float* __restrict__ out,
                                unsigned short* __restrict__ xbf)
{
    int wave = threadIdx.x >> 6, lane = threadIdx.x & 63;
    int row  = blockIdx.x * 4 + wave;
    const float4 v = *(const float4*)&x[(size_t)row * D_DIM + lane * 4];
    if (xbf) {
        u16x4 p; p[0]=f2bf(v.x); p[1]=f2bf(v.y); p[2]=f2bf(v.z); p[3]=f2bf(v.w);
        *(u16x4*)&xbf[(size_t)row * D_DIM + lane * 4] = p;
    }
    float s = v.x * v.x + v.y * v.y + v.z * v.z + v.w * v.w;
    #pragma unroll
    for (int m = 32; m >= 1; m >>= 1) s += __shfl_down(s, m, 64);
    if (lane == 0) out[row] = s;
}

// ---------------------------------------------------------------------------
// Fused two-pass MFMA sweep, barrier-free K-loop.
// Block: 128 queries x all 1024 codes. Wave w owns 32 queries (2 A-tiles of
// 16), A-fragments held in registers for the FULL D (16 x bf16x8 = 64 VGPR),
// converted from fp32 z in-flight. B-fragments read directly from the
// pre-converted bf16 codebook (L2-resident, 512 KB) -- no LDS tiles, no
// __syncthreads in the K-loop (R5: 256 barriers/block -> both pipes <14%).
// Pass A: s1 = ||e||^2 - 2*dot_bf16, per-query running min in registers,
// cross-lane reduce -> thr = min + DELTA (registers only, block covers all K).
// Pass B: bitwise-identical recompute (same A regs, same ebf, same MFMA
// chain) -> winner's s1 == rmin is always admitted; DELTA only covers
// bf16-vs-fp32 order divergence (4e-3 ~ 20 sigma, passed R5). Candidates go
// to an LDS list, then exact fp32 rescore with ref op order
// fl(fl(zz-2dot)+en) and first-index ties via packed u64 atomicMin.
// Layouts (m91, passed R5): A[m=lane&15][k=quad*8+j]; C/D col(code)=lane&15,
// row(query)=quad*4+reg.
__launch_bounds__(256, 2)
__global__ void sweep_kernel(const float* __restrict__ z,
                             const float* __restrict__ embed,
                             const unsigned short* __restrict__ ebf,
                             const float* __restrict__ enorm,
                             const float* __restrict__ zz,
                             unsigned long long* __restrict__ pack)
{
    __shared__ unsigned list[SW_CAP];
    __shared__ int lcnt;

    const int t = threadIdx.x;
    const int w = t >> 6, lane = t & 63;
    const int col = lane & 15, quad = lane >> 4;
    const int qbase = blockIdx.x * 128;

    if (t == 0) lcnt = 0;

    // A fragments: full D for 2 query-tiles, fp32 -> bf16 in-flight
    bf16x8 A[2][8];
    #pragma unroll
    for (int tile = 0; tile < 2; ++tile) {
        const float* src = &z[(size_t)(qbase + w*32 + tile*16 + col) * D_DIM + quad*8];
        #pragma unroll
        for (int ds = 0; ds < 8; ++ds) {
            float4 a = *(const float4*)&src[ds*32];
            float4 b = *(const float4*)&src[ds*32 + 4];
            A[tile][ds] = pack8(a, b);
        }
    }

    float rmin[2][4];
    #pragma unroll
    for (int tile = 0; tile < 2; ++tile)
        #pragma unroll
        for (int rg = 0; rg < 4; ++rg) rmin[tile][rg] = FLT_MAX;

    // ---- PASS A: per-query min of s1 over all 1024 codes ----
    for (int kc = 0; kc < 16; ++kc) {
        f32x4 acc[2][4];
        #pragma unroll
        for (int tile = 0; tile < 2; ++tile)
            #pragma unroll
            for (int ct = 0; ct < 4; ++ct) acc[tile][ct] = (f32x4){0.f,0.f,0.f,0.f};
        #pragma unroll
        for (int ds = 0; ds < 8; ++ds) {
            bf16x8 B[4];
            #pragma unroll
            for (int ct = 0; ct < 4; ++ct)
                B[ct] = *(const bf16x8*)&ebf[(size_t)(kc*64 + ct*16 + col) * D_DIM + ds*32 + quad*8];
            #pragma unroll
            for (int ct = 0; ct < 4; ++ct) {
                acc[0][ct] = __builtin_amdgcn_mfma_f32_16x16x32_bf16(A[0][ds], B[ct], acc[0][ct], 0, 0, 0);
                acc[1][ct] = __builtin_amdgcn_mfma_f32_16x16x32_bf16(A[1][ds], B[ct], acc[1][ct], 0, 0, 0);
            }
        }
        #pragma unroll
        for (int ct = 0; ct < 4; ++ct) {
            float en = enorm[kc*64 + ct*16 + col];
            #pragma unroll
            for (int tile = 0; tile < 2; ++tile)
                #pragma unroll
                for (int rg = 0; rg < 4; ++rg)
                    rmin[tile][rg] = fminf(rmin[tile][rg], en - 2.0f * acc[tile][ct][rg]);
        }
    }

    // cross-lane min within each 16-lane col group -> threshold (registers)
    float thr[2][4];
    #pragma unroll
    for (int tile = 0; tile < 2; ++tile)
        #pragma unroll
        for (int rg = 0; rg < 4; ++rg) {
            float v = rmin[tile][rg];
            #pragma unroll
            for (int m = 1; m < 16; m <<= 1) v = fminf(v, __shfl_xor(v, m, 64));
            thr[tile][rg] = v + DELTA;
        }

    __syncthreads();   // lcnt init visible before pushes

    // ---- PASS B: bitwise-identical recompute, filter, collect ----
    for (int kc = 0; kc < 16; ++kc) {
        f32x4 acc[2][4];
        #pragma unroll
        for (int tile = 0; tile < 2; ++tile)
            #pragma unroll
            for (int ct = 0; ct < 4; ++ct) acc[tile][ct] = (f32x4){0.f,0.f,0.f,0.f};
        #pragma unroll
        for (int ds = 0; ds < 8; ++ds) {
            bf16x8 B[4];
            #pragma unroll
            for (int ct = 0; ct < 4; ++ct)
                B[ct] = *(const bf16x8*)&ebf[(size_t)(kc*64 + ct*16 + col) * D_DIM + ds*32 + quad*8];
            #pragma unroll
            for (int ct = 0; ct < 4; ++ct) {
                acc[0][ct] = __builtin_amdgcn_mfma_f32_16x16x32_bf16(A[0][ds], B[ct], acc[0][ct], 0, 0, 0);
                acc[1][ct] = __builtin_amdgcn_mfma_f32_16x16x32_bf16(A[1][ds], B[ct], acc[1][ct], 0, 0, 0);
            }
        }
        #pragma unroll
        for (int ct = 0; ct < 4; ++ct) {
            int k = kc*64 + ct*16 + col;
            float en = enorm[k];
            #pragma unroll
            for (int tile = 0; tile < 2; ++tile)
                #pragma unroll
                for (int rg = 0; rg < 4; ++rg) {
                    float s1 = en - 2.0f * acc[tile][ct][rg];
                    if (s1 <= thr[tile][rg]) {
                        int qloc = w*32 + tile*16 + quad*4 + rg;
                        int pos = atomicAdd(&lcnt, 1);
                        if (pos < SW_CAP) {
                            list[pos] = ((unsigned)qloc << 10) | (unsigned)k;
                        } else {
                            // overflow fallback: exact rescore inline (rare)
                            int qg = qbase + qloc;
                            double dd = 0.0;
                            for (int d = 0; d < D_DIM; d += 4) {
                                float4 a = *(const float4*)&z[(size_t)qg*D_DIM + d];
                                float4 b = *(const float4*)&embed[(size_t)k*D_DIM + d];
                                dd += (double)a.x*b.x + (double)a.y*b.y
                                    + (double)a.z*b.z + (double)a.w*b.w;
                            }
                            float s = (zz[qg] - 2.0f*(float)dd) + en;
                            unsigned long long pk =
                                ((unsigned long long)__float_as_uint(s) << 32) | (unsigned)k;
                            atomicMin(&pack[qg], pk);
                        }
                    }
                }
        }
    }

    // ---- exact rescore of candidates: one wave per entry, lane covers 4 d ----
    __syncthreads();
    int cnt = min(lcnt, SW_CAP);
    for (int e = w; e < cnt; e += 4) {
        unsigned ent = list[e];
        int qloc = (int)(ent >> 10), k = (int)(ent & 1023u);
        int qg = qbase + qloc;
        float4 a = *(const float4*)&z[(size_t)qg*D_DIM + lane*4];
        float4 b = *(const float4*)&embed[(size_t)k*D_DIM + lane*4];
        double dd = (double)a.x*b.x + (double)a.y*b.y
                  + (double)a.z*b.z + (double)a.w*b.w;
        #pragma unroll
        for (int m = 32; m >= 1; m >>= 1)
            dd += __shfl_xor(dd, m, 64);
        if (lane == 0) {
            float s = (zz[qg] - 2.0f*(float)dd) + enorm[k];  // ref op order
            unsigned long long pk =
                ((unsigned long long)__float_as_uint(s) << 32) | (unsigned)k;
            atomicMin(&pack[qg], pk);
        }
    }
}

// ---------------------------------------------------------------------------
// unpack winner, write idx (int + float), histogram counts
__global__ void unpack_kernel(const unsigned long long* __restrict__ pack,
                              int* __restrict__ idx_i,
                              float* __restrict__ idx_f,
                              int* __restrict__ icnt)
{
    int n = blockIdx.x * 256 + threadIdx.x;
    int k = (int)(pack[n] & 0xffffffffull);
    idx_i[n] = k;
    idx_f[n] = (float)k;
    atomicAdd(&icnt[k], 1);
}

// ---------------------------------------------------------------------------
// exclusive scan of counts (1 block x 1024) -> offsets + fill cursor + float counts
__global__ void scan_kernel(const int* __restrict__ icnt,
                            int* __restrict__ offs,
                            int* __restrict__ offw,
                            float* __restrict__ cntf)
{
    __shared__ int s[1024];
    int t = threadIdx.x;
    int v0 = icnt[t];
    s[t] = v0;
    __syncthreads();
    for (int d = 1; d < 1024; d <<= 1) {
        int v = (t >= d) ? s[t - d] : 0;
        __syncthreads();
        s[t] += v;
        __syncthreads();
    }
    int excl = s[t] - v0;
    offs[t] = excl;
    offw[t] = excl;
    cntf[t] = (float)v0;
}

// ---------------------------------------------------------------------------
// build CSR permutation (order within a code arbitrary; accum uses double)
__global__ void fill_kernel(const int* __restrict__ idx,
                            int* __restrict__ offw,
                            int* __restrict__ perm)
{
    int n = blockIdx.x * 256 + threadIdx.x;
    int k = idx[n];
    int pos = atomicAdd(&offw[k], 1);
    perm[pos] = n;
}

// ---------------------------------------------------------------------------
// gather q = embed[idx], write q_st = z + (q - z), accumulate sum((z-q)^2)
// into 1024 double buckets
__global__ void qst_loss_kernel(const float* __restrict__ z,
                                const float* __restrict__ embed,
                                const int* __restrict__ idx,
                                float* __restrict__ qst,
                                double* __restrict__ lossb)
{
    int tid = blockIdx.x * blockDim.x + threadIdx.x;
    int e0  = tid * 4;
    int n   = e0 >> 8, d = e0 & 255;
    int k   = idx[n];
    const float4 q4 = *(const float4*)&embed[(size_t)k * D_DIM + d];
    const float4 z4 = *(const float4*)&z[e0];
    float4 o;
    o.x = z4.x + (q4.x - z4.x);
    o.y = z4.y + (q4.y - z4.y);
    o.z = z4.z + (q4.z - z4.z);
    o.w = z4.w + (q4.w - z4.w);
    *(float4*)&qst[e0] = o;
    float dx = z4.x - q4.x, dy = z4.y - q4.y, dz = z4.z - q4.z, dw = z4.w - q4.w;
    float s = dx * dx + dy * dy + dz * dz + dw * dw;
    #pragma unroll
    for (int m = 32; m >= 1; m >>= 1) s += __shfl_down(s, m, 64);
    __shared__ float ps[4];
    int wave = threadIdx.x >> 6, lane = threadIdx.x & 63;
    if (lane == 0) ps[wave] = s;
    __syncthreads();
    if (threadIdx.x == 0)
        atomicAdd(&lossb[blockIdx.x & 1023],
                  (double)((ps[0] + ps[1]) + (ps[2] + ps[3])));
}

// ---------------------------------------------------------------------------
// new_count, n = sum(new_count), cs, vq_loss finalize (single block of 1024)
__global__ void fin_counts_kernel(const float* __restrict__ ema_count,
                                  const float* __restrict__ cntf,
                                  const double* __restrict__ lossb,
                                  float* __restrict__ out_count,
                                  float* __restrict__ out_loss,
                                  float* __restrict__ cs)
{
    __shared__ float  red[1024];
    __shared__ double dred[1024];
    int t = threadIdx.x;
    float c = 0.99f * ema_count[t] + 0.01f * cntf[t];
    out_count[t] = c;
    red[t]  = c;
    dred[t] = lossb[t];
    __syncthreads();
    for (int s = 512; s >= 1; s >>= 1) {
        if (t < s) { red[t] += red[t + s]; dred[t] += dred[t + s]; }
        __syncthreads();
    }
    float n = red[0];
    cs[t] = (c + 1e-5f) / (n + 1024.0f * 1e-5f) * n;
    if (t == 0) {
        float m = (float)(dred[0] / (double)((size_t)N_Q * D_DIM));
        out_loss[0] = m + 0.25f * m;   // codebook + BETA*commit, bitwise equal halves
    }
}

// ---------------------------------------------------------------------------
// per-code: dw[k,d] = sum over members of z (double accum, 4-way ILP), then
// EMA + normalize. One block per code; thread t handles column d=t.
__global__ void accum_embed_kernel(const float* __restrict__ z,
                                   const int* __restrict__ perm,
                                   const int* __restrict__ icnt,
                                   const int* __restrict__ offs,
                                   const float* __restrict__ cs,
                                   const float* __restrict__ ema_w,
                                   float* __restrict__ out_embed,
                                   float* __restrict__ out_emaw)
{
    __shared__ int rows[256];
    int k = blockIdx.x, t = threadIdx.x;
    int cnt = icnt[k], off = offs[k];
    double a0 = 0.0, a1 = 0.0, a2 = 0.0, a3 = 0.0;
    for (int base = 0; base < cnt; base += 256) {
        int m = min(256, cnt - base);
        __syncthreads();
        if (t < m) rows[t] = perm[off + base + t];
        __syncthreads();
        int r = 0;
        for (; r + 4 <= m; r += 4) {
            a0 += (double)z[(size_t)rows[r+0] * D_DIM + t];
            a1 += (double)z[(size_t)rows[r+1] * D_DIM + t];
            a2 += (double)z[(size_t)rows[r+2] * D_DIM + t];
            a3 += (double)z[(size_t)rows[r+3] * D_DIM + t];
        }
        for (; r < m; ++r) a0 += (double)z[(size_t)rows[r] * D_DIM + t];
    }
    double acc = (a0 + a1) + (a2 + a3);
    float w = 0.99f * ema_w[(size_t)k * D_DIM + t] + 0.01f * (float)acc;
    out_emaw[(size_t)k * D_DIM + t]  = w;
    out_embed[(size_t)k * D_DIM + t] = w / cs[k];
}

// ---------------------------------------------------------------------------
extern "C" void kernel_launch(void* const* d_in, const int* in_sizes, int n_in,
                              void* d_out, int out_size, void* d_ws, size_t ws_size,
                              hipStream_t stream)
{
    const float* z          = (const float*)d_in[0];
    const float* embed      = (const float*)d_in[1];
    const float* ema_count  = (const float*)d_in[2];
    const float* ema_weight = (const float*)d_in[3];
    float* out = (float*)d_out;
    char*  ws  = (char*)d_ws;

    int*      ws_idx  = (int*)(ws + WS_IDX);
    float*    ws_zz   = (float*)(ws + WS_ZZ);
    int*      ws_perm = (int*)(ws + WS_PERM);
    unsigned long long* ws_pack = (unsigned long long*)(ws + WS_PACK);
    float*    ws_en   = (float*)(ws + WS_EN);
    int*      ws_icnt = (int*)(ws + WS_ICNT);
    int*      ws_offs = (int*)(ws + WS_OFFS);
    int*      ws_offw = (int*)(ws + WS_OFFW);
    float*    ws_cntf = (float*)(ws + WS_CNTF);
    float*    ws_cs   = (float*)(ws + WS_CS);
    double*   ws_lb   = (double*)(ws + WS_LOSSB);
    unsigned short* ws_ebf = (unsigned short*)(ws + WS_EBF);

    hipMemsetAsync(ws + WS_PACK,  0xFF, (size_t)N_Q * 8, stream);
    hipMemsetAsync(ws + WS_ICNT,  0, 4096, stream);
    hipMemsetAsync(ws + WS_LOSSB, 0, 8192, stream);

    rownorm2_kernel<<<K_CODES / 4, 256, 0, stream>>>(embed, ws_en, ws_ebf);
    rownorm2_kernel<<<N_Q / 4,     256, 0, stream>>>(z, ws_zz, nullptr);

    sweep_kernel<<<N_Q / 128, 256, 0, stream>>>(z, embed, ws_ebf, ws_en, ws_zz,
                                                ws_pack);

    unpack_kernel<<<N_Q / 256, 256, 0, stream>>>(ws_pack, ws_idx,
                                                 out + OUT_IDX, ws_icnt);
    scan_kernel<<<1, 1024, 0, stream>>>(ws_icnt, ws_offs, ws_offw, ws_cntf);
    fill_kernel<<<N_Q / 256, 256, 0, stream>>>(ws_idx, ws_offw, ws_perm);
    qst_loss_kernel<<<(N_Q * (D_DIM / 4)) / 256, 256, 0, stream>>>(
        z, embed, ws_idx, out + OUT_QST, ws_lb);
    fin_counts_kernel<<<1, 1024, 0, stream>>>(ema_count, ws_cntf, ws_lb,
                                              out + OUT_COUNT, out + OUT_LOSS, ws_cs);
    accum_embed_kernel<<<K_CODES, 256, 0, stream>>>(z, ws_perm, ws_icnt, ws_offs,
                                                    ws_cs, ema_weight,
                                                    out + OUT_EMBED, out + OUT_EMAW);
}